// Round 2
// baseline (713.682 us; speedup 1.0000x reference)
//
#include <hip/hip_runtime.h>

#define SS 2048
#define DD 1024
#define HH 16
#define DHD 64
#define HSN (HH * SS)  // 32768
#define LOG2E 1.44269504088896340736f

typedef __bf16 bf16x8 __attribute__((ext_vector_type(8)));
typedef __bf16 bf16x4 __attribute__((ext_vector_type(4)));
typedef float f32x4 __attribute__((ext_vector_type(4)));
typedef unsigned int u32;

__device__ __forceinline__ void glds16(const void* g, void* l) {
  __builtin_amdgcn_global_load_lds(
      (const __attribute__((address_space(1))) u32*)(const u32*)g,
      (__attribute__((address_space(3))) u32*)(u32*)l, 16, 0, 0);
}

// ---------------- fp32 -> bf16 convert ----------------
__global__ __launch_bounds__(256) void cvt_bf16_kernel(const float* __restrict__ in,
                                                       __bf16* __restrict__ out, int n4) {
  int i = blockIdx.x * 256 + threadIdx.x;
  if (i >= n4) return;
  const float4 v = ((const float4*)in)[i];
  bf16x4 r;
  r[0] = (__bf16)v.x; r[1] = (__bf16)v.y; r[2] = (__bf16)v.z; r[3] = (__bf16)v.w;
  *(bf16x4*)&out[(long)i * 4] = r;
}

// ---------------- 128x128 NT GEMM body (m97 pattern): C = A[M,K] * B[N,K]^T ----------------
// M=SS rows via blockIdx.y, N=DD cols via blockIdx.x, K=DD.
template <int OUTF32>
__device__ __forceinline__ void gemm128_body(const __bf16* __restrict__ A,
                                             const __bf16* __restrict__ B,
                                             void* __restrict__ Cout, float scale) {
  __shared__ alignas(16) __bf16 As[128 * 32];
  __shared__ alignas(16) __bf16 Bs[128 * 32];
  const int tid = threadIdx.x;
  const int lane = tid & 63;
  const int wave = tid >> 6;
  const long m0 = (long)blockIdx.y * 128;
  const long n0 = (long)blockIdx.x * 128;
  const int wm = (wave >> 1) * 64;
  const int wn = (wave & 1) * 64;
  const int g = lane >> 4, r16 = lane & 15;
  const int srow = tid >> 2, sseg = (tid & 3) * 8;  // 32-col rows: 4 segs of 16B

  f32x4 acc[4][4] = {};

  for (int k0 = 0; k0 < DD; k0 += 32) {
#pragma unroll
    for (int it = 0; it < 2; ++it) {
      const int row = srow + it * 64;
      glds16(&A[(m0 + row) * DD + k0 + sseg], &As[row * 32 + sseg]);
      glds16(&B[(n0 + row) * DD + k0 + sseg], &Bs[row * 32 + sseg]);
    }
    __syncthreads();
    bf16x8 af[4], bfr[4];
#pragma unroll
    for (int r = 0; r < 4; ++r) af[r] = *(const bf16x8*)&As[(wm + r * 16 + r16) * 32 + g * 8];
#pragma unroll
    for (int c = 0; c < 4; ++c) bfr[c] = *(const bf16x8*)&Bs[(wn + c * 16 + r16) * 32 + g * 8];
#pragma unroll
    for (int r = 0; r < 4; ++r)
#pragma unroll
      for (int c = 0; c < 4; ++c)
        acc[r][c] = __builtin_amdgcn_mfma_f32_16x16x32_bf16(af[r], bfr[c], acc[r][c], 0, 0, 0);
    __syncthreads();
  }

#pragma unroll
  for (int r = 0; r < 4; ++r)
#pragma unroll
    for (int c = 0; c < 4; ++c)
#pragma unroll
      for (int i = 0; i < 4; ++i) {
        const long row = m0 + wm + r * 16 + g * 4 + i;
        const long col = n0 + wn + c * 16 + r16;
        const float v = acc[r][c][i] * scale;
        if (OUTF32) ((float*)Cout)[row * DD + col] = v;
        else        ((__bf16*)Cout)[row * DD + col] = (__bf16)v;
      }
}

__global__ __launch_bounds__(256) void gemm_qkv(const __bf16* __restrict__ A,
                                                const __bf16* __restrict__ B0,
                                                const __bf16* __restrict__ B1,
                                                const __bf16* __restrict__ B2,
                                                __bf16* C0, __bf16* C1, __bf16* C2,
                                                float s0) {
  const __bf16* B = blockIdx.z == 0 ? B0 : (blockIdx.z == 1 ? B1 : B2);
  __bf16* C = blockIdx.z == 0 ? C0 : (blockIdx.z == 1 ? C1 : C2);
  gemm128_body<0>(A, B, C, blockIdx.z == 0 ? s0 : 1.0f);
}

__global__ __launch_bounds__(256) void gemm_o(const __bf16* __restrict__ A,
                                              const __bf16* __restrict__ B,
                                              float* __restrict__ C) {
  gemm128_body<1>(A, B, C, 1.0f);
}

// ---------------- bf16 transpose: out[c][r] = in[r][c] ----------------
__global__ __launch_bounds__(256) void transpose_bf16(const __bf16* __restrict__ in,
                                                      __bf16* __restrict__ out,
                                                      int R, int C) {
  __shared__ __bf16 t[64][72];
  const int tid = threadIdx.x;
  const long r0 = (long)blockIdx.y * 64;
  const long c0 = (long)blockIdx.x * 64;
  const int row = tid >> 2;
#pragma unroll
  for (int it = 0; it < 2; ++it) {
    const int seg = (tid & 3) * 8 + it * 32;
    *(bf16x8*)&t[row][seg] = *(const bf16x8*)&in[(r0 + row) * C + c0 + seg];
  }
  __syncthreads();
#pragma unroll
  for (int it = 0; it < 2; ++it) {
    const int seg = (tid & 3) * 8 + it * 32;
    bf16x8 v;
#pragma unroll
    for (int j = 0; j < 8; ++j) v[j] = t[seg + j][row];
    *(bf16x8*)&out[(c0 + row) * R + r0 + seg] = v;
  }
}

// ---------------- flash attention, split-KV ----------------
// Q pre-scaled by (1/sqrt(DH))*log2(e); softmax in exp2 domain.
// Block = 64 q rows x 1 head x 1 kv-split. Wave = 16 q rows. kv tile 64.
// Outputs unnormalized O partials + per-row (m, l).
__global__ __launch_bounds__(256) void attn_kernel(
    const __bf16* __restrict__ Q, const __bf16* __restrict__ K,
    const __bf16* __restrict__ Vt, const float* __restrict__ bias,
    const int* __restrict__ mask, float* __restrict__ Opart,
    float* __restrict__ Mpart, float* __restrict__ Lpart) {
  __shared__ alignas(16) __bf16 Ks[64][72];   // kv x dh, pad 72 (144B rows: 2-way free)
  __shared__ alignas(16) __bf16 Vts[64][72];  // d x kv, pad 72
  __shared__ alignas(16) __bf16 Ps[4][16][72];
  const int tid = threadIdx.x;
  const int lane = tid & 63;
  const int wave = tid >> 6;
  const int h = blockIdx.y;
  const int z = blockIdx.z;
  const int q0 = blockIdx.x * 64 + wave * 16;
  const int g = lane >> 4, r16 = lane & 15;
  const int kvlen = SS / gridDim.z;
  const int kvbeg = z * kvlen;

  bf16x8 qf[2];
#pragma unroll
  for (int m = 0; m < 2; ++m)
    qf[m] = *(const bf16x8*)&Q[(long)(q0 + r16) * DD + h * DHD + m * 32 + g * 8];

  f32x4 o[4] = {};
  float mrow[4], lsum[4];
#pragma unroll
  for (int i = 0; i < 4; ++i) { mrow[i] = -__builtin_inff(); lsum[i] = 0.f; }

  const int srow = tid >> 2;  // 0..63

  for (int kv0 = kvbeg; kv0 < kvbeg + kvlen; kv0 += 64) {
    __syncthreads();  // protect LDS from previous iteration's readers
#pragma unroll
    for (int it = 0; it < 2; ++it) {
      const int seg = (tid & 3) + it * 4;
      *(bf16x8*)&Ks[srow][seg * 8] =
          *(const bf16x8*)&K[(long)(kv0 + srow) * DD + h * DHD + seg * 8];
      *(bf16x8*)&Vts[srow][seg * 8] =
          *(const bf16x8*)&Vt[(long)(h * DHD + srow) * SS + kv0 + seg * 8];
    }
    __syncthreads();

    // QK^T: 4 t-chunks of 16 kv
    f32x4 s[4];
#pragma unroll
    for (int t = 0; t < 4; ++t) {
      bf16x8 kf0 = *(const bf16x8*)&Ks[t * 16 + r16][g * 8];
      bf16x8 kf1 = *(const bf16x8*)&Ks[t * 16 + r16][32 + g * 8];
      f32x4 acc = {};
      acc = __builtin_amdgcn_mfma_f32_16x16x32_bf16(qf[0], kf0, acc, 0, 0, 0);
      s[t] = __builtin_amdgcn_mfma_f32_16x16x32_bf16(qf[1], kf1, acc, 0, 0, 0);
    }

    // bias + mask (issue all loads up front)
    float sv[4][4];
#pragma unroll
    for (int t = 0; t < 4; ++t) {
      const int kcol = kv0 + t * 16 + r16;
#pragma unroll
      for (int i = 0; i < 4; ++i) {
        const int qrow = q0 + g * 4 + i;
        const float bv = bias[(long)qrow * HSN + h * SS + kcol];
        const int mv = mask[(long)qrow * SS + kcol];
        sv[t][i] = mv ? s[t][i] + bv * LOG2E : -1e38f;
      }
    }

    // online softmax, one reduction per q-row (combined over t)
#pragma unroll
    for (int i = 0; i < 4; ++i) {
      float m4 = fmaxf(fmaxf(sv[0][i], sv[1][i]), fmaxf(sv[2][i], sv[3][i]));
      m4 = fmaxf(m4, __shfl_xor(m4, 1));
      m4 = fmaxf(m4, __shfl_xor(m4, 2));
      m4 = fmaxf(m4, __shfl_xor(m4, 4));
      m4 = fmaxf(m4, __shfl_xor(m4, 8));
      const float mnew = fmaxf(mrow[i], m4);
      const float alpha = exp2f(mrow[i] - mnew);
      const float p0 = exp2f(sv[0][i] - mnew);
      const float p1 = exp2f(sv[1][i] - mnew);
      const float p2 = exp2f(sv[2][i] - mnew);
      const float p3 = exp2f(sv[3][i] - mnew);
      float ps = (p0 + p1) + (p2 + p3);
      ps += __shfl_xor(ps, 1);
      ps += __shfl_xor(ps, 2);
      ps += __shfl_xor(ps, 4);
      ps += __shfl_xor(ps, 8);
      lsum[i] = lsum[i] * alpha + ps;
      mrow[i] = mnew;
#pragma unroll
      for (int db = 0; db < 4; ++db) o[db][i] *= alpha;
      Ps[wave][g * 4 + i][r16]      = (__bf16)p0;
      Ps[wave][g * 4 + i][16 + r16] = (__bf16)p1;
      Ps[wave][g * 4 + i][32 + r16] = (__bf16)p2;
      Ps[wave][g * 4 + i][48 + r16] = (__bf16)p3;
    }

    // PV: two 32-kv halves
#pragma unroll
    for (int kh = 0; kh < 2; ++kh) {
      bf16x8 pf = *(const bf16x8*)&Ps[wave][r16][kh * 32 + g * 8];
#pragma unroll
      for (int db = 0; db < 4; ++db) {
        bf16x8 vf = *(const bf16x8*)&Vts[db * 16 + r16][kh * 32 + g * 8];
        o[db] = __builtin_amdgcn_mfma_f32_16x16x32_bf16(pf, vf, o[db], 0, 0, 0);
      }
    }
  }

  // write partials (unnormalized O, log2-domain m, linear l)
#pragma unroll
  for (int db = 0; db < 4; ++db)
#pragma unroll
    for (int i = 0; i < 4; ++i) {
      const long row = q0 + g * 4 + i;
      Opart[((long)z * SS + row) * DD + h * DHD + db * 16 + r16] = o[db][i];
    }
  if (r16 == 0) {
#pragma unroll
    for (int i = 0; i < 4; ++i) {
      const long row = q0 + g * 4 + i;
      Mpart[((long)z * SS + row) * HH + h] = mrow[i];
      Lpart[((long)z * SS + row) * HH + h] = lsum[i];
    }
  }
}

// ---------------- split-KV combine -> bf16 context ----------------
__global__ __launch_bounds__(256) void attn_combine(const float* __restrict__ Opart,
                                                    const float* __restrict__ Mpart,
                                                    const float* __restrict__ Lpart,
                                                    __bf16* __restrict__ Aout, int nsplit) {
  const int q = blockIdx.y;
  const int idx = blockIdx.x * 256 + threadIdx.x;  // 0..1023
  const int h = idx >> 6;
  float M = -__builtin_inff();
  float mz[8];
  for (int zz = 0; zz < nsplit; ++zz) {
    mz[zz] = Mpart[((long)zz * SS + q) * HH + h];
    M = fmaxf(M, mz[zz]);
  }
  float num = 0.f, den = 0.f;
  for (int zz = 0; zz < nsplit; ++zz) {
    const float w = exp2f(mz[zz] - M);
    num += w * Opart[((long)zz * SS + q) * DD + idx];
    den += w * Lpart[((long)zz * SS + q) * HH + h];
  }
  Aout[(long)q * DD + idx] = (__bf16)(num / den);
}

// ---------------- residual + LayerNorm ----------------
__global__ __launch_bounds__(256) void ln_kernel(const float* __restrict__ attn_out,
                                                 const float* __restrict__ x,
                                                 const float* __restrict__ w,
                                                 const float* __restrict__ b,
                                                 float* __restrict__ out) {
  const long row = blockIdx.x;
  const int tid = threadIdx.x;
  float v[4];
  float s = 0.f, s2 = 0.f;
#pragma unroll
  for (int j = 0; j < 4; ++j) {
    const int d = tid + j * 256;
    const float r = attn_out[row * DD + d] + x[row * DD + d];
    v[j] = r; s += r; s2 += r * r;
  }
#pragma unroll
  for (int off = 1; off < 64; off <<= 1) {
    s  += __shfl_xor(s, off);
    s2 += __shfl_xor(s2, off);
  }
  __shared__ float ss[4], ss2[4];
  if ((tid & 63) == 0) { ss[tid >> 6] = s; ss2[tid >> 6] = s2; }
  __syncthreads();
  s = ss[0] + ss[1] + ss[2] + ss[3];
  s2 = ss2[0] + ss2[1] + ss2[2] + ss2[3];
  const float mean = s * (1.f / DD);
  const float var = s2 * (1.f / DD) - mean * mean;
  const float inv = rsqrtf(var + 1e-5f);
#pragma unroll
  for (int j = 0; j < 4; ++j) {
    const int d = tid + j * 256;
    out[row * DD + d] = (v[j] - mean) * inv * w[d] + b[d];
  }
}

// ---------------- host launch ----------------
extern "C" void kernel_launch(void* const* d_in, const int* in_sizes, int n_in,
                              void* d_out, int out_size, void* d_ws, size_t ws_size,
                              hipStream_t stream) {
  const float* x    = (const float*)d_in[0];
  const float* bias = (const float*)d_in[1];
  const int*   mask = (const int*)d_in[2];
  const float* Wq   = (const float*)d_in[3];
  const float* Wk   = (const float*)d_in[4];
  const float* Wv   = (const float*)d_in[5];
  const float* Wo   = (const float*)d_in[6];
  const float* lnw  = (const float*)d_in[7];
  const float* lnb  = (const float*)d_in[8];
  float* out = (float*)d_out;

  char* ws = (char*)d_ws;
  const size_t MB = 1024 * 1024;
  __bf16* xb   = (__bf16*)(ws + 0);
  __bf16* Wqb  = (__bf16*)(ws + 4 * MB);
  __bf16* Wkb  = (__bf16*)(ws + 6 * MB);
  __bf16* Wvb  = (__bf16*)(ws + 8 * MB);
  __bf16* Wob  = (__bf16*)(ws + 10 * MB);
  __bf16* Qb   = (__bf16*)(ws + 12 * MB);
  __bf16* Kb   = (__bf16*)(ws + 16 * MB);
  __bf16* Vb   = (__bf16*)(ws + 20 * MB);
  __bf16* Vtb  = (__bf16*)(ws + 24 * MB);
  __bf16* Atnb = (__bf16*)(ws + 28 * MB);
  float*  AOut = (float*)(ws + 32 * MB);   // 8 MB
  const size_t base = 40 * MB;

  // choose split count that fits the workspace
  int nsplit = 4;
  while (nsplit > 1 &&
         base + (size_t)nsplit * (8 * MB + 2 * (size_t)SS * HH * 4) > ws_size)
    nsplit >>= 1;
  float* Opart = (float*)(ws + base);
  float* Mpart = (float*)(ws + base + (size_t)nsplit * 8 * MB);
  float* Lpart = Mpart + (size_t)nsplit * SS * HH;

  // converts
  cvt_bf16_kernel<<<dim3(SS * DD / 1024), dim3(256), 0, stream>>>(x, xb, SS * DD / 4);
  cvt_bf16_kernel<<<dim3(DD * DD / 1024), dim3(256), 0, stream>>>(Wq, Wqb, DD * DD / 4);
  cvt_bf16_kernel<<<dim3(DD * DD / 1024), dim3(256), 0, stream>>>(Wk, Wkb, DD * DD / 4);
  cvt_bf16_kernel<<<dim3(DD * DD / 1024), dim3(256), 0, stream>>>(Wv, Wvb, DD * DD / 4);
  cvt_bf16_kernel<<<dim3(DD * DD / 1024), dim3(256), 0, stream>>>(Wo, Wob, DD * DD / 4);

  // QKV projections (fused via grid.z); Q scaled by 0.125*log2(e)
  gemm_qkv<<<dim3(DD / 128, SS / 128, 3), dim3(256), 0, stream>>>(
      xb, Wqb, Wkb, Wvb, Qb, Kb, Vb, 0.125f * LOG2E);

  // V^T [D, S]
  transpose_bf16<<<dim3(DD / 64, SS / 64), dim3(256), 0, stream>>>(Vb, Vtb, SS, DD);

  // split-KV flash attention + combine
  attn_kernel<<<dim3(SS / 64, HH, nsplit), dim3(256), 0, stream>>>(
      Qb, Kb, Vtb, bias, mask, Opart, Mpart, Lpart);
  attn_combine<<<dim3(DD / 256, SS), dim3(256), 0, stream>>>(Opart, Mpart, Lpart, Atnb, nsplit);

  // out projection (fp32 out)
  gemm_o<<<dim3(DD / 128, SS / 128), dim3(256), 0, stream>>>(Atnb, Wob, AOut);

  // residual + LN
  ln_kernel<<<dim3(SS), dim3(256), 0, stream>>>(AOut, x, lnw, lnb, out);
}

// Round 3
// 488.913 us; speedup vs baseline: 1.4597x; 1.4597x over previous
//
#include <hip/hip_runtime.h>

#define SS 2048
#define DD 1024
#define HH 16
#define DHD 64
#define HSN (HH * SS)  // 32768
#define LOG2E 1.44269504088896340736f

typedef __bf16 bf16x8 __attribute__((ext_vector_type(8)));
typedef __bf16 bf16x4 __attribute__((ext_vector_type(4)));
typedef float f32x4 __attribute__((ext_vector_type(4)));
typedef unsigned int u32;

__device__ __forceinline__ void glds16(const void* g, void* l) {
  __builtin_amdgcn_global_load_lds(
      (const __attribute__((address_space(1))) u32*)(const u32*)g,
      (__attribute__((address_space(3))) u32*)(u32*)l, 16, 0, 0);
}

// ---------------- fused fp32 -> bf16 converts (x, Wq, Wk, Wv, Wo) ----------------
__global__ __launch_bounds__(256) void cvt_all_kernel(const float* __restrict__ x,
                                                      const float* __restrict__ Wq,
                                                      const float* __restrict__ Wk,
                                                      const float* __restrict__ Wv,
                                                      const float* __restrict__ Wo,
                                                      __bf16* xb, __bf16* Wqb, __bf16* Wkb,
                                                      __bf16* Wvb, __bf16* Wob) {
  const int z = blockIdx.z;
  const int n4 = (z == 0 ? SS * DD : DD * DD) / 4;
  const int i = blockIdx.x * 256 + threadIdx.x;
  if (i >= n4) return;
  const float* in = z == 0 ? x : (z == 1 ? Wq : (z == 2 ? Wk : (z == 3 ? Wv : Wo)));
  __bf16* out = z == 0 ? xb : (z == 1 ? Wqb : (z == 2 ? Wkb : (z == 3 ? Wvb : Wob)));
  const float4 v = ((const float4*)in)[i];
  bf16x4 r;
  r[0] = (__bf16)v.x; r[1] = (__bf16)v.y; r[2] = (__bf16)v.z; r[3] = (__bf16)v.w;
  *(bf16x4*)&out[(long)i * 4] = r;
}

// ---------------- 128x128 NT GEMM body (m97 pattern): C = A[M,K] * B[N,K]^T ----------------
template <int OUTF32>
__device__ __forceinline__ void gemm128_body(const __bf16* __restrict__ A,
                                             const __bf16* __restrict__ B,
                                             void* __restrict__ Cout, float scale) {
  __shared__ alignas(16) __bf16 As[128 * 32];
  __shared__ alignas(16) __bf16 Bs[128 * 32];
  const int tid = threadIdx.x;
  const int lane = tid & 63;
  const int wave = tid >> 6;
  const long m0 = (long)blockIdx.y * 128;
  const long n0 = (long)blockIdx.x * 128;
  const int wm = (wave >> 1) * 64;
  const int wn = (wave & 1) * 64;
  const int g = lane >> 4, r16 = lane & 15;
  const int srow = tid >> 2, sseg = (tid & 3) * 8;

  f32x4 acc[4][4] = {};

  for (int k0 = 0; k0 < DD; k0 += 32) {
#pragma unroll
    for (int it = 0; it < 2; ++it) {
      const int row = srow + it * 64;
      glds16(&A[(m0 + row) * DD + k0 + sseg], &As[row * 32 + sseg]);
      glds16(&B[(n0 + row) * DD + k0 + sseg], &Bs[row * 32 + sseg]);
    }
    __syncthreads();
    bf16x8 af[4], bfr[4];
#pragma unroll
    for (int r = 0; r < 4; ++r) af[r] = *(const bf16x8*)&As[(wm + r * 16 + r16) * 32 + g * 8];
#pragma unroll
    for (int c = 0; c < 4; ++c) bfr[c] = *(const bf16x8*)&Bs[(wn + c * 16 + r16) * 32 + g * 8];
#pragma unroll
    for (int r = 0; r < 4; ++r)
#pragma unroll
      for (int c = 0; c < 4; ++c)
        acc[r][c] = __builtin_amdgcn_mfma_f32_16x16x32_bf16(af[r], bfr[c], acc[r][c], 0, 0, 0);
    __syncthreads();
  }

#pragma unroll
  for (int r = 0; r < 4; ++r)
#pragma unroll
    for (int c = 0; c < 4; ++c)
#pragma unroll
      for (int i = 0; i < 4; ++i) {
        const long row = m0 + wm + r * 16 + g * 4 + i;
        const long col = n0 + wn + c * 16 + r16;
        const float v = acc[r][c][i] * scale;
        if (OUTF32) ((float*)Cout)[row * DD + col] = v;
        else        ((__bf16*)Cout)[row * DD + col] = (__bf16)v;
      }
}

__global__ __launch_bounds__(256) void gemm_qkv(const __bf16* __restrict__ A,
                                                const __bf16* __restrict__ B0,
                                                const __bf16* __restrict__ B1,
                                                const __bf16* __restrict__ B2,
                                                __bf16* C0, __bf16* C1, __bf16* C2,
                                                float s0) {
  const __bf16* B = blockIdx.z == 0 ? B0 : (blockIdx.z == 1 ? B1 : B2);
  __bf16* C = blockIdx.z == 0 ? C0 : (blockIdx.z == 1 ? C1 : C2);
  gemm128_body<0>(A, B, C, blockIdx.z == 0 ? s0 : 1.0f);
}

__global__ __launch_bounds__(256) void gemm_o(const __bf16* __restrict__ A,
                                              const __bf16* __restrict__ B,
                                              float* __restrict__ C) {
  gemm128_body<1>(A, B, C, 1.0f);
}

// ---------------- bf16 transpose: out[c][r] = in[r][c] ----------------
__global__ __launch_bounds__(256) void transpose_bf16(const __bf16* __restrict__ in,
                                                      __bf16* __restrict__ out,
                                                      int R, int C) {
  __shared__ __bf16 t[64][72];
  const int tid = threadIdx.x;
  const long r0 = (long)blockIdx.y * 64;
  const long c0 = (long)blockIdx.x * 64;
  const int row = tid >> 2;
#pragma unroll
  for (int it = 0; it < 2; ++it) {
    const int seg = (tid & 3) * 8 + it * 32;
    *(bf16x8*)&t[row][seg] = *(const bf16x8*)&in[(r0 + row) * C + c0 + seg];
  }
  __syncthreads();
#pragma unroll
  for (int it = 0; it < 2; ++it) {
    const int seg = (tid & 3) * 8 + it * 32;
    bf16x8 v;
#pragma unroll
    for (int j = 0; j < 8; ++j) v[j] = t[seg + j][row];
    *(bf16x8*)&out[(c0 + row) * R + r0 + seg] = v;
  }
}

// ---------------- transposed flash attention ----------------
// Computes S^T = K.Q^T per tile so the C-layout puts 4 regs on consecutive kv
// at fixed q (q = lane&15). Bias/mask load as float4/int4; P^T stored to LDS
// with 8B writes; PV computed as O^T = V^T . P^T; output vectorized over d.
// Q pre-scaled by (1/sqrt(DH))*log2(e); softmax in exp2 domain.
__global__ __launch_bounds__(256) void attn_kernel(
    const __bf16* __restrict__ Q, const __bf16* __restrict__ K,
    const __bf16* __restrict__ Vt, const float* __restrict__ bias,
    const int* __restrict__ mask, __bf16* __restrict__ Aout) {
  __shared__ alignas(16) __bf16 Ks[64][72];   // kv x dh
  __shared__ alignas(16) __bf16 Vts[64][72];  // d x kv
  __shared__ alignas(16) __bf16 Ps[4][16][72];  // per-wave P[q][kv]
  const int tid = threadIdx.x;
  const int lane = tid & 63;
  const int wave = tid >> 6;
  const int h = blockIdx.y;
  const int q0 = blockIdx.x * 64 + wave * 16;
  const int g = lane >> 4, r16 = lane & 15;
  const int myq = q0 + r16;

  // Q as B-fragment: B[k=dh=g*8+j][n=q=r16]
  bf16x8 qf[2];
#pragma unroll
  for (int c = 0; c < 2; ++c)
    qf[c] = *(const bf16x8*)&Q[(long)myq * DD + h * DHD + c * 32 + g * 8];

  f32x4 o[4] = {};                 // o[db][i]: O^T[d = db*16+g*4+i][q=r16]
  float mrow = -__builtin_inff();  // per-lane (q = r16)
  float lsum = 0.f;

  const int srow = tid >> 2;  // 0..63

  for (int kv0 = 0; kv0 < SS; kv0 += 64) {
    __syncthreads();
#pragma unroll
    for (int it = 0; it < 2; ++it) {
      const int seg = (tid & 3) + it * 4;
      *(bf16x8*)&Ks[srow][seg * 8] =
          *(const bf16x8*)&K[(long)(kv0 + srow) * DD + h * DHD + seg * 8];
      *(bf16x8*)&Vts[srow][seg * 8] =
          *(const bf16x8*)&Vt[(long)(h * DHD + srow) * SS + kv0 + seg * 8];
    }

    // bias/mask vector loads (independent of LDS; overlap with barrier drain)
    float4 bv[4];
    int4 mv[4];
#pragma unroll
    for (int t = 0; t < 4; ++t) {
      const int kvi = kv0 + t * 16 + g * 4;
      bv[t] = *(const float4*)&bias[(long)myq * HSN + h * SS + kvi];
      mv[t] = *(const int4*)&mask[(long)myq * SS + kvi];
    }
    __syncthreads();

    // S^T = K.Q^T : 4 chunks of 16 kv
    f32x4 s[4];
#pragma unroll
    for (int t = 0; t < 4; ++t) {
      bf16x8 kf0 = *(const bf16x8*)&Ks[t * 16 + r16][g * 8];
      bf16x8 kf1 = *(const bf16x8*)&Ks[t * 16 + r16][32 + g * 8];
      f32x4 acc = {};
      acc = __builtin_amdgcn_mfma_f32_16x16x32_bf16(kf0, qf[0], acc, 0, 0, 0);
      s[t] = __builtin_amdgcn_mfma_f32_16x16x32_bf16(kf1, qf[1], acc, 0, 0, 0);
    }

    // masked biased logits (log2 domain)
    float sv[4][4];
#pragma unroll
    for (int t = 0; t < 4; ++t) {
      sv[t][0] = mv[t].x ? s[t][0] + bv[t].x * LOG2E : -1e38f;
      sv[t][1] = mv[t].y ? s[t][1] + bv[t].y * LOG2E : -1e38f;
      sv[t][2] = mv[t].z ? s[t][2] + bv[t].z * LOG2E : -1e38f;
      sv[t][3] = mv[t].w ? s[t][3] + bv[t].w * LOG2E : -1e38f;
    }

    // online softmax for q = r16: local reduce over 16 regs + 2 shuffles
    float m4 = -1e38f;
#pragma unroll
    for (int t = 0; t < 4; ++t)
#pragma unroll
      for (int i = 0; i < 4; ++i) m4 = fmaxf(m4, sv[t][i]);
    m4 = fmaxf(m4, __shfl_xor(m4, 16));
    m4 = fmaxf(m4, __shfl_xor(m4, 32));
    const float mnew = fmaxf(mrow, m4);
    const float alpha = exp2f(mrow - mnew);
    float ps = 0.f;
    float p[4][4];
#pragma unroll
    for (int t = 0; t < 4; ++t)
#pragma unroll
      for (int i = 0; i < 4; ++i) {
        p[t][i] = exp2f(sv[t][i] - mnew);
        ps += p[t][i];
      }
    ps += __shfl_xor(ps, 16);
    ps += __shfl_xor(ps, 32);
    lsum = lsum * alpha + ps;
    mrow = mnew;
#pragma unroll
    for (int db = 0; db < 4; ++db) o[db] *= alpha;

    // store P^T as P[q][kv] (8B contiguous over i)
#pragma unroll
    for (int t = 0; t < 4; ++t) {
      bf16x4 pb;
#pragma unroll
      for (int i = 0; i < 4; ++i) pb[i] = (__bf16)p[t][i];
      *(bf16x4*)&Ps[wave][r16][t * 16 + g * 4] = pb;
    }

    // O^T += V^T . P^T : two 32-kv halves
#pragma unroll
    for (int kh = 0; kh < 2; ++kh) {
      bf16x8 pf = *(const bf16x8*)&Ps[wave][r16][kh * 32 + g * 8];
#pragma unroll
      for (int db = 0; db < 4; ++db) {
        bf16x8 vf = *(const bf16x8*)&Vts[db * 16 + r16][kh * 32 + g * 8];
        o[db] = __builtin_amdgcn_mfma_f32_16x16x32_bf16(vf, pf, o[db], 0, 0, 0);
      }
    }
  }

  const float rn = 1.f / lsum;
#pragma unroll
  for (int db = 0; db < 4; ++db) {
    bf16x4 r;
#pragma unroll
    for (int i = 0; i < 4; ++i) r[i] = (__bf16)(o[db][i] * rn);
    *(bf16x4*)&Aout[(long)myq * DD + h * DHD + db * 16 + g * 4] = r;
  }
}

// ---------------- residual + LayerNorm ----------------
__global__ __launch_bounds__(256) void ln_kernel(const float* __restrict__ attn_out,
                                                 const float* __restrict__ x,
                                                 const float* __restrict__ w,
                                                 const float* __restrict__ b,
                                                 float* __restrict__ out) {
  const long row = blockIdx.x;
  const int tid = threadIdx.x;
  float v[4];
  float s = 0.f, s2 = 0.f;
#pragma unroll
  for (int j = 0; j < 4; ++j) {
    const int d = tid + j * 256;
    const float r = attn_out[row * DD + d] + x[row * DD + d];
    v[j] = r; s += r; s2 += r * r;
  }
#pragma unroll
  for (int off = 1; off < 64; off <<= 1) {
    s  += __shfl_xor(s, off);
    s2 += __shfl_xor(s2, off);
  }
  __shared__ float ss[4], ss2[4];
  if ((tid & 63) == 0) { ss[tid >> 6] = s; ss2[tid >> 6] = s2; }
  __syncthreads();
  s = ss[0] + ss[1] + ss[2] + ss[3];
  s2 = ss2[0] + ss2[1] + ss2[2] + ss2[3];
  const float mean = s * (1.f / DD);
  const float var = s2 * (1.f / DD) - mean * mean;
  const float inv = rsqrtf(var + 1e-5f);
#pragma unroll
  for (int j = 0; j < 4; ++j) {
    const int d = tid + j * 256;
    out[row * DD + d] = (v[j] - mean) * inv * w[d] + b[d];
  }
}

// ---------------- host launch ----------------
extern "C" void kernel_launch(void* const* d_in, const int* in_sizes, int n_in,
                              void* d_out, int out_size, void* d_ws, size_t ws_size,
                              hipStream_t stream) {
  const float* x    = (const float*)d_in[0];
  const float* bias = (const float*)d_in[1];
  const int*   mask = (const int*)d_in[2];
  const float* Wq   = (const float*)d_in[3];
  const float* Wk   = (const float*)d_in[4];
  const float* Wv   = (const float*)d_in[5];
  const float* Wo   = (const float*)d_in[6];
  const float* lnw  = (const float*)d_in[7];
  const float* lnb  = (const float*)d_in[8];
  float* out = (float*)d_out;

  char* ws = (char*)d_ws;
  const size_t MB = 1024 * 1024;
  __bf16* xb   = (__bf16*)(ws + 0);
  __bf16* Wqb  = (__bf16*)(ws + 4 * MB);
  __bf16* Wkb  = (__bf16*)(ws + 6 * MB);
  __bf16* Wvb  = (__bf16*)(ws + 8 * MB);
  __bf16* Wob  = (__bf16*)(ws + 10 * MB);
  __bf16* Qb   = (__bf16*)(ws + 12 * MB);
  __bf16* Kb   = (__bf16*)(ws + 16 * MB);
  __bf16* Vb   = (__bf16*)(ws + 20 * MB);
  __bf16* Vtb  = (__bf16*)(ws + 24 * MB);
  __bf16* Atnb = (__bf16*)(ws + 28 * MB);
  float*  AOut = (float*)(ws + 32 * MB);

  // fused converts (z: 0=x [2048 blocks], 1..4=weights [1024 blocks])
  cvt_all_kernel<<<dim3(SS * DD / 1024, 1, 5), dim3(256), 0, stream>>>(
      x, Wq, Wk, Wv, Wo, xb, Wqb, Wkb, Wvb, Wob);

  // QKV projections (fused via grid.z); Q scaled by 0.125*log2(e)
  gemm_qkv<<<dim3(DD / 128, SS / 128, 3), dim3(256), 0, stream>>>(
      xb, Wqb, Wkb, Wvb, Qb, Kb, Vb, 0.125f * LOG2E);

  // V^T [D, S]
  transpose_bf16<<<dim3(DD / 64, SS / 64), dim3(256), 0, stream>>>(Vb, Vtb, SS, DD);

  // transposed flash attention, direct bf16 context output
  attn_kernel<<<dim3(SS / 64, HH), dim3(256), 0, stream>>>(Qb, Kb, Vtb, bias, mask, Atnb);

  // out projection (fp32 out)
  gemm_o<<<dim3(DD / 128, SS / 128), dim3(256), 0, stream>>>(Atnb, Wob, AOut);

  // residual + LN
  ln_kernel<<<dim3(SS), dim3(256), 0, stream>>>(AOut, x, lnw, lnb, out);
}